// Round 2
// baseline (12959.444 us; speedup 1.0000x reference)
//
#include <hip/hip_runtime.h>

#define N_NODES 50000
#define N_EDGES 400000
#define EMB 32
#define NREL 8
#define NLAYER 5
#define NPB 12          // nodes per block in layer kernel
#define NROWS 42        // 0..31 P, 32 S_tot, 33..40 S_r, 41 hid-stage/h_dst
#define LT 384          // 12 half-waves

// ---------------- setup kernels ----------------

__global__ __launch_bounds__(256) void zero_kernel(int* __restrict__ p, int n) {
    int i = blockIdx.x * 256 + threadIdx.x;
    if (i < n) p[i] = 0;
}

__global__ __launch_bounds__(256) void hist_kernel(const int* __restrict__ ei,
                                                   const int* __restrict__ et,
                                                   int* __restrict__ deg,
                                                   int* __restrict__ relcnt) {
    int e = blockIdx.x * 256 + threadIdx.x;
    if (e < N_EDGES) {
        int d = ei[N_EDGES + e];           // dst = edge_index[1]
        atomicAdd(&deg[d], 1);
        atomicAdd(&relcnt[d * NREL + et[e]], 1);
    }
}

__global__ __launch_bounds__(1024) void scan_kernel(const int* __restrict__ deg,
                                                    int* __restrict__ row_ptr) {
    __shared__ int wtot[16];
    __shared__ int pwt[16];
    __shared__ int carry_s;
    int tid = threadIdx.x;
    int lane = tid & 63;
    int w = tid >> 6;
    if (tid == 0) carry_s = 0;
    __syncthreads();
    for (int base = 0; base < N_NODES; base += 1024) {
        int i = base + tid;
        int v = (i < N_NODES) ? deg[i] : 0;
        int incl = v;
        #pragma unroll
        for (int off = 1; off < 64; off <<= 1) {
            int t = __shfl_up(incl, off, 64);
            if (lane >= off) incl += t;
        }
        if (lane == 63) wtot[w] = incl;
        __syncthreads();
        if (tid == 0) {
            int c = carry_s, run = 0;
            #pragma unroll
            for (int j = 0; j < 16; j++) { pwt[j] = c + run; run += wtot[j]; }
            carry_s = c + run;
        }
        __syncthreads();
        if (i < N_NODES) row_ptr[i] = pwt[w] + incl - v;
        __syncthreads();
    }
    if (tid == 0) row_ptr[N_NODES] = carry_s;
}

__global__ __launch_bounds__(256) void inv_kernel(const int* __restrict__ deg,
                                                  const int* __restrict__ relcnt,
                                                  float* __restrict__ invdeg,
                                                  float* __restrict__ invcnt) {
    int n = blockIdx.x * 256 + threadIdx.x;
    if (n < N_NODES) {
        int d = deg[n];
        invdeg[n] = 1.0f / (float)(d > 0 ? d : 1);
        #pragma unroll
        for (int r = 0; r < NREL; r++) {
            int c = relcnt[n * NREL + r];
            invcnt[n * NREL + r] = 1.0f / (float)(c > 0 ? c : 1);
        }
    }
}

__global__ __launch_bounds__(256) void scatter_kernel(const int* __restrict__ ei,
                                                      const int* __restrict__ et,
                                                      const float* __restrict__ ed,
                                                      const int* __restrict__ row_ptr,
                                                      int* __restrict__ cursor,
                                                      int2* __restrict__ edge2) {
    int e = blockIdx.x * 256 + threadIdx.x;
    if (e < N_EDGES) {
        int d = ei[N_EDGES + e];
        int pos = row_ptr[d] + atomicAdd(&cursor[d], 1);
        edge2[pos] = make_int2(ei[e] | (et[e] << 16), __float_as_int(ed[e]));
    }
}

// ---------------- fc: h0 = relu(x @ fc_W + fc_b) ----------------

__global__ __launch_bounds__(256) void fc_kernel(const float* __restrict__ x,
                                                 const float* __restrict__ W,
                                                 const float* __restrict__ b,
                                                 float* __restrict__ h) {
    __shared__ __align__(16) float xt[8][EMB];
    int tid = threadIdx.x;
    int nl = tid >> 5, lane = tid & 31;
    int n0 = blockIdx.x * 8;
    xt[tid >> 5][tid & 31] = x[n0 * EMB + tid];
    __syncthreads();
    float acc = b[lane];
    #pragma unroll
    for (int i = 0; i < EMB; i++) acc += xt[nl][i] * W[i * EMB + lane];
    h[(n0 + nl) * EMB + lane] = fmaxf(acc, 0.0f);
}

// ---------------- fused layer kernel ----------------
// Edge phase (half-wave per node, lane = input feature i):
//   P[k][i]  = sum_e hid_e[k] * h[src_e][i]      (k = 0..31)
//   S_r[i]   = sum_{e in rel r} h[src_e][i]
// Contraction phase (lane = output feature o, W columns in registers):
//   out_n[o] = invdeg*(sum_{k,i} P[k][i] W2[k,i*32+o] + sum_i Stot[i] b2[i*32+o])
//   out_r[o] = sum_r sum_i invcnt_r*S_r[i]*rgcnW[r][i*32+o]
// Epilogue: roots (h_d @ nn_root / rgcn_root), biases, relus, residual.
__global__ __launch_bounds__(LT) void layer_kernel(
    const float* __restrict__ h,
    const int2* __restrict__ edge2,
    const int* __restrict__ row_ptr,
    const float* __restrict__ invdeg,
    const float* __restrict__ invcnt,
    const float* __restrict__ W1,
    const float* __restrict__ b1,
    const float* __restrict__ W2,
    const float* __restrict__ b2,
    const float* __restrict__ rgcnW_l,
    const float* __restrict__ rgcnRoot_l,
    const float* __restrict__ rgcnBias_l,
    const float* __restrict__ nnRoot_l,
    const float* __restrict__ nnBias_l,
    float* __restrict__ hout)
{
    __shared__ __align__(16) float Prows[NPB][NROWS][EMB];   // 64512 B

    const int tid = threadIdx.x;
    const int hw = tid >> 5, lane = tid & 31;
    const int n = blockIdx.x * NPB + hw;
    const bool valid = (n < N_NODES);

    // ---------- edge phase ----------
    float P[32], S[NREL];
    #pragma unroll
    for (int k = 0; k < 32; k++) P[k] = 0.0f;
    #pragma unroll
    for (int r = 0; r < NREL; r++) S[r] = 0.0f;

    float w10 = W1[lane];
    float b1v = b1[lane];

    if (valid) {
        int pb = row_ptr[n], pe = row_ptr[n + 1];
        if (pb < pe) {
            int2 e0 = edge2[pb];
            float hv0 = h[(e0.x & 0xFFFF) * EMB + lane];
            for (int p = pb; p < pe; p++) {
                int pn = (p + 1 < pe) ? (p + 1) : (pe - 1);
                int2 e1 = edge2[pn];                              // prefetch
                float hv1 = h[(e1.x & 0xFFFF) * EMB + lane];      // prefetch gather
                int r = (e0.x >> 16) & 7;
                float dist = __int_as_float(e0.y);
                float hid = fmaxf(fmaf(dist, w10, W1[(1 + r) * EMB + lane] + b1v), 0.0f);
                Prows[hw][41][lane] = hid;   // half-wave broadcast stage
                #pragma unroll
                for (int j = 0; j < 8; j++) {
                    float4 h4 = ((const float4*)&Prows[hw][41][0])[j];
                    P[4 * j + 0] = fmaf(h4.x, hv0, P[4 * j + 0]);
                    P[4 * j + 1] = fmaf(h4.y, hv0, P[4 * j + 1]);
                    P[4 * j + 2] = fmaf(h4.z, hv0, P[4 * j + 2]);
                    P[4 * j + 3] = fmaf(h4.w, hv0, P[4 * j + 3]);
                }
                #pragma unroll
                for (int rr = 0; rr < NREL; rr++)
                    S[rr] += (r == rr) ? hv0 : 0.0f;
                e0 = e1; hv0 = hv1;
            }
        }
    }

    // write reduction rows (pre-scaled)
    float idg = valid ? invdeg[n] : 0.0f;
    #pragma unroll
    for (int k = 0; k < 32; k++) Prows[hw][k][lane] = P[k] * idg;
    float stot = 0.0f;
    #pragma unroll
    for (int r = 0; r < NREL; r++) stot += S[r];
    Prows[hw][32][lane] = stot * idg;
    #pragma unroll
    for (int r = 0; r < NREL; r++) {
        float ic = valid ? invcnt[n * NREL + r] : 0.0f;
        Prows[hw][33 + r][lane] = S[r] * ic;
    }
    Prows[hw][41][lane] = valid ? h[n * EMB + lane] : 0.0f;   // h_dst row
    __syncthreads();

    // ---------- contraction (lane = output column o) ----------
    float accN[NPB], accR[NPB];
    #pragma unroll
    for (int i = 0; i < NPB; i++) { accN[i] = 0.0f; accR[i] = 0.0f; }

    #pragma unroll
    for (int pass = 0; pass < 2; pass++) {
        const int row0 = 24 * pass + 2 * hw;
        const int row1 = row0 + 1;
        const float* s0 = (row0 < 32) ? (W2 + row0 * 1024)
                        : (row0 == 32) ? b2
                        : (row0 <= 40) ? (rgcnW_l + (row0 - 33) * 1024) : nullptr;
        const float* s1 = (row1 < 32) ? (W2 + row1 * 1024)
                        : (row1 == 32) ? b2
                        : (row1 <= 40) ? (rgcnW_l + (row1 - 33) * 1024) : nullptr;
        float Wa[32], Wb[32];
        #pragma unroll
        for (int i = 0; i < 32; i++) Wa[i] = s0 ? s0[i * EMB + lane] : 0.0f;
        #pragma unroll
        for (int i = 0; i < 32; i++) Wb[i] = s1 ? s1[i * EMB + lane] : 0.0f;
        const int r0c = (row0 <= 41) ? row0 : 41;   // clamp (garbage*0 ok)
        const int r1c = (row1 <= 41) ? row1 : 41;
        const bool n0 = (row0 <= 32), n1 = (row1 <= 32);
        #pragma unroll
        for (int nd = 0; nd < NPB; nd++) {
            const float4* Ra = (const float4*)&Prows[nd][r0c][0];
            const float4* Rb = (const float4*)&Prows[nd][r1c][0];
            float pa = 0.0f, pb = 0.0f;
            #pragma unroll
            for (int j = 0; j < 8; j++) {
                float4 a4 = Ra[j];
                float4 b4 = Rb[j];
                pa = fmaf(a4.x, Wa[4 * j + 0], pa);
                pa = fmaf(a4.y, Wa[4 * j + 1], pa);
                pa = fmaf(a4.z, Wa[4 * j + 2], pa);
                pa = fmaf(a4.w, Wa[4 * j + 3], pa);
                pb = fmaf(b4.x, Wb[4 * j + 0], pb);
                pb = fmaf(b4.y, Wb[4 * j + 1], pb);
                pb = fmaf(b4.z, Wb[4 * j + 2], pb);
                pb = fmaf(b4.w, Wb[4 * j + 3], pb);
            }
            accN[nd] += n0 ? pa : 0.0f;
            accR[nd] += n0 ? 0.0f : pa;
            accN[nd] += n1 ? pb : 0.0f;
            accR[nd] += n1 ? 0.0f : pb;
        }
    }

    // ---------- root terms (read Prows row 41 BEFORE Red aliasing) ----------
    float rootN = 0.0f, rootR = 0.0f;
    {
        const float4* hd4 = (const float4*)&Prows[hw][41][0];
        #pragma unroll
        for (int j = 0; j < 8; j++) {
            float4 v = hd4[j];
            rootN = fmaf(v.x, nnRoot_l[(4 * j + 0) * EMB + lane], rootN);
            rootN = fmaf(v.y, nnRoot_l[(4 * j + 1) * EMB + lane], rootN);
            rootN = fmaf(v.z, nnRoot_l[(4 * j + 2) * EMB + lane], rootN);
            rootN = fmaf(v.w, nnRoot_l[(4 * j + 3) * EMB + lane], rootN);
            rootR = fmaf(v.x, rgcnRoot_l[(4 * j + 0) * EMB + lane], rootR);
            rootR = fmaf(v.y, rgcnRoot_l[(4 * j + 1) * EMB + lane], rootR);
            rootR = fmaf(v.z, rgcnRoot_l[(4 * j + 2) * EMB + lane], rootR);
            rootR = fmaf(v.w, rgcnRoot_l[(4 * j + 3) * EMB + lane], rootR);
        }
    }
    float hd_o = Prows[hw][41][lane];
    __syncthreads();

    // ---------- cross-half-wave reduction (alias Red over Prows) ----------
    float* Red = &Prows[0][0][0];
    #pragma unroll
    for (int nd = 0; nd < NPB; nd++) {
        Red[(hw * NPB + nd) * EMB + lane] = accN[nd];
        Red[(NPB * NPB + hw * NPB + nd) * EMB + lane] = accR[nd];
    }
    __syncthreads();

    if (valid) {
        float sn = 0.0f, sr = 0.0f;
        #pragma unroll
        for (int w = 0; w < NPB; w++) sn += Red[(w * NPB + hw) * EMB + lane];
        #pragma unroll
        for (int w = 0; w < NPB; w++) sr += Red[(NPB * NPB + w * NPB + hw) * EMB + lane];
        float o_r = fmaxf(sr + rootR + rgcnBias_l[lane], 0.0f);
        float o_n = fmaxf(sn + rootN + nnBias_l[lane], 0.0f);
        hout[n * EMB + lane] = hd_o + o_r + o_n;
    }
}

// ---------------- launch ----------------

extern "C" void kernel_launch(void* const* d_in, const int* in_sizes, int n_in,
                              void* d_out, int out_size, void* d_ws, size_t ws_size,
                              hipStream_t stream) {
    const float* x        = (const float*)d_in[0];
    const int*   ei       = (const int*)d_in[1];
    const int*   et       = (const int*)d_in[2];
    const float* ed       = (const float*)d_in[3];
    const float* fcW      = (const float*)d_in[4];
    const float* fcb      = (const float*)d_in[5];
    const float* rgcnW    = (const float*)d_in[6];
    const float* rgcnRoot = (const float*)d_in[7];
    const float* rgcnBias = (const float*)d_in[8];
    const float* W1       = (const float*)d_in[9];
    const float* b1       = (const float*)d_in[10];
    const float* W2       = (const float*)d_in[11];
    const float* b2       = (const float*)d_in[12];
    const float* nnRoot   = (const float*)d_in[13];
    const float* nnBias   = (const float*)d_in[14];

    float* ws = (float*)d_ws;
    float* h_a    = ws;  ws += (size_t)N_NODES * EMB;
    float* h_b    = ws;  ws += (size_t)N_NODES * EMB;
    float* invdeg = ws;  ws += (size_t)N_NODES;
    float* invcnt = ws;  ws += (size_t)N_NODES * NREL;
    int2* edge2   = (int2*)ws;     ws += (size_t)N_EDGES * 2;
    int* row_ptr  = (int*)ws;      ws += (size_t)(N_NODES + 1);
    int* deg      = (int*)ws;      ws += (size_t)N_NODES;       // deg..cursor contiguous
    int* relcnt   = (int*)ws;      ws += (size_t)N_NODES * NREL;
    int* cursor   = (int*)ws;      ws += (size_t)N_NODES;
    (void)in_sizes; (void)n_in; (void)out_size; (void)ws_size;

    zero_kernel<<<(10 * N_NODES + 255) / 256, 256, 0, stream>>>(deg, 10 * N_NODES);
    hist_kernel<<<(N_EDGES + 255) / 256, 256, 0, stream>>>(ei, et, deg, relcnt);
    scan_kernel<<<1, 1024, 0, stream>>>(deg, row_ptr);
    inv_kernel<<<(N_NODES + 255) / 256, 256, 0, stream>>>(deg, relcnt, invdeg, invcnt);
    scatter_kernel<<<(N_EDGES + 255) / 256, 256, 0, stream>>>(ei, et, ed, row_ptr,
                                                              cursor, edge2);
    fc_kernel<<<N_NODES / 8, 256, 0, stream>>>(x, fcW, fcb, h_a);

    const int grid = (N_NODES + NPB - 1) / NPB;
    const float* hin = h_a;
    float* houtb = h_b;
    for (int l = 0; l < NLAYER; l++) {
        float* dst = (l == NLAYER - 1) ? (float*)d_out : houtb;
        layer_kernel<<<grid, LT, 0, stream>>>(
            hin, edge2, row_ptr, invdeg, invcnt, W1, b1, W2, b2,
            rgcnW + (size_t)l * NREL * EMB * EMB,
            rgcnRoot + (size_t)l * EMB * EMB,
            rgcnBias + (size_t)l * EMB,
            nnRoot + (size_t)l * EMB * EMB,
            nnBias + (size_t)l * EMB,
            dst);
        float* old_in = (float*)hin;
        hin = dst;
        houtb = old_in;
    }
}

// Round 3
// 969.556 us; speedup vs baseline: 13.3664x; 13.3664x over previous
//
#include <hip/hip_runtime.h>

#define N_NODES 50000
#define N_EDGES 400000
#define EMB 32
#define NREL 8
#define NLAYER 5
#define NPB 8           // nodes per block (half-wave each)
#define NROWS 42        // 0..31 P, 32 Stot, 33..40 S_r, 41 hid-stage / h_dst

// ---------------- setup kernels ----------------

__global__ __launch_bounds__(256) void zero_kernel(int* __restrict__ p, int n) {
    int i = blockIdx.x * 256 + threadIdx.x;
    if (i < n) p[i] = 0;
}

__global__ __launch_bounds__(256) void hist_kernel(const int* __restrict__ ei,
                                                   const int* __restrict__ et,
                                                   int* __restrict__ deg,
                                                   int* __restrict__ relcnt) {
    int e = blockIdx.x * 256 + threadIdx.x;
    if (e < N_EDGES) {
        int d = ei[N_EDGES + e];           // dst = edge_index[1]
        atomicAdd(&deg[d], 1);
        atomicAdd(&relcnt[d * NREL + et[e]], 1);
    }
}

__global__ __launch_bounds__(1024) void scan_kernel(const int* __restrict__ deg,
                                                    int* __restrict__ row_ptr) {
    __shared__ int wtot[16];
    __shared__ int pwt[16];
    __shared__ int carry_s;
    int tid = threadIdx.x;
    int lane = tid & 63;
    int w = tid >> 6;
    if (tid == 0) carry_s = 0;
    __syncthreads();
    for (int base = 0; base < N_NODES; base += 1024) {
        int i = base + tid;
        int v = (i < N_NODES) ? deg[i] : 0;
        int incl = v;
        #pragma unroll
        for (int off = 1; off < 64; off <<= 1) {
            int t = __shfl_up(incl, off, 64);
            if (lane >= off) incl += t;
        }
        if (lane == 63) wtot[w] = incl;
        __syncthreads();
        if (tid == 0) {
            int c = carry_s, run = 0;
            #pragma unroll
            for (int j = 0; j < 16; j++) { pwt[j] = c + run; run += wtot[j]; }
            carry_s = c + run;
        }
        __syncthreads();
        if (i < N_NODES) row_ptr[i] = pwt[w] + incl - v;
        __syncthreads();
    }
    if (tid == 0) row_ptr[N_NODES] = carry_s;
}

__global__ __launch_bounds__(256) void inv_kernel(const int* __restrict__ deg,
                                                  const int* __restrict__ relcnt,
                                                  float* __restrict__ invdeg,
                                                  float* __restrict__ invcnt) {
    int n = blockIdx.x * 256 + threadIdx.x;
    if (n < N_NODES) {
        int d = deg[n];
        invdeg[n] = 1.0f / (float)(d > 0 ? d : 1);
        #pragma unroll
        for (int r = 0; r < NREL; r++) {
            int c = relcnt[n * NREL + r];
            invcnt[n * NREL + r] = 1.0f / (float)(c > 0 ? c : 1);
        }
    }
}

__global__ __launch_bounds__(256) void scatter_kernel(const int* __restrict__ ei,
                                                      const int* __restrict__ et,
                                                      const float* __restrict__ ed,
                                                      const int* __restrict__ row_ptr,
                                                      int* __restrict__ cursor,
                                                      int2* __restrict__ edge2) {
    int e = blockIdx.x * 256 + threadIdx.x;
    if (e < N_EDGES) {
        int d = ei[N_EDGES + e];
        int pos = row_ptr[d] + atomicAdd(&cursor[d], 1);
        edge2[pos] = make_int2(ei[e] | (et[e] << 16), __float_as_int(ed[e]));
    }
}

// ---------------- fc: h0 = relu(x @ fc_W + fc_b) ----------------

__global__ __launch_bounds__(256) void fc_kernel(const float* __restrict__ x,
                                                 const float* __restrict__ W,
                                                 const float* __restrict__ b,
                                                 float* __restrict__ h) {
    __shared__ __align__(16) float xt[8][EMB];
    int tid = threadIdx.x;
    int nl = tid >> 5, lane = tid & 31;
    int n0 = blockIdx.x * 8;
    xt[tid >> 5][tid & 31] = x[n0 * EMB + tid];
    __syncthreads();
    float acc = b[lane];
    #pragma unroll
    for (int i = 0; i < EMB; i++) acc += xt[nl][i] * W[i * EMB + lane];
    h[(n0 + nl) * EMB + lane] = fmaxf(acc, 0.0f);
}

// ---------------- fused layer kernel ----------------
// Edge phase (half-wave per node, lane = input feature i):
//   P[k][i]  = sum_e hid_e[k] * h[src_e][i]   (k = 0..31, hid = edge-MLP hidden)
//   S_r[i]   = sum_{e in rel r} h[src_e][i]
// Rows written to LDS pre-scaled: P*invdeg, Stot*invdeg, S_r*invcnt_r.
// Contraction (lane = output o): half-wave hw owns rows {hw+8j}, caches the
// 32-float W column-slice in VGPRs, sweeps 8 nodes with broadcast b128 P reads.
// Epilogue: roots, biases, relus, residual, cross-half-wave LDS reduction.
__global__ __launch_bounds__(256) void layer_kernel(
    const float* __restrict__ h,
    const int2* __restrict__ edge2,
    const int* __restrict__ row_ptr,
    const float* __restrict__ invdeg,
    const float* __restrict__ invcnt,
    const float* __restrict__ W1,
    const float* __restrict__ b1,
    const float* __restrict__ W2,
    const float* __restrict__ b2,
    const float* __restrict__ rgcnW_l,
    const float* __restrict__ rgcnRoot_l,
    const float* __restrict__ rgcnBias_l,
    const float* __restrict__ nnRoot_l,
    const float* __restrict__ nnBias_l,
    float* __restrict__ hout)
{
    __shared__ __align__(16) float Prows[NPB][NROWS][EMB];   // 43008 B -> 3 blocks/CU

    const int tid = threadIdx.x;
    const int hw = tid >> 5, lane = tid & 31;
    const int n = blockIdx.x * NPB + hw;   // N divisible by 8: no guard

    // ---------- edge phase ----------
    float P[32], S[NREL];
    #pragma unroll
    for (int k = 0; k < 32; k++) P[k] = 0.0f;
    #pragma unroll
    for (int r = 0; r < NREL; r++) S[r] = 0.0f;

    const float w10 = W1[lane];
    const float b1v = b1[lane];

    const int pb = row_ptr[n], pe = row_ptr[n + 1];
    if (pb < pe) {
        int2 e0 = edge2[pb];
        float hv0 = h[(e0.x & 0xFFFF) * EMB + lane];
        for (int p = pb; p < pe; p++) {
            int pn = (p + 1 < pe) ? (p + 1) : (pe - 1);
            int2 e1 = edge2[pn];                              // prefetch
            float hv1 = h[(e1.x & 0xFFFF) * EMB + lane];      // prefetch gather
            int r = (e0.x >> 16) & 7;
            float dist = __int_as_float(e0.y);
            float hid = fmaxf(fmaf(dist, w10, W1[(1 + r) * EMB + lane] + b1v), 0.0f);
            Prows[hw][41][lane] = hid;   // half-wave broadcast stage (same-wave, no barrier)
            #pragma unroll
            for (int j = 0; j < 8; j++) {
                float4 h4 = ((const float4*)&Prows[hw][41][0])[j];
                P[4 * j + 0] = fmaf(h4.x, hv0, P[4 * j + 0]);
                P[4 * j + 1] = fmaf(h4.y, hv0, P[4 * j + 1]);
                P[4 * j + 2] = fmaf(h4.z, hv0, P[4 * j + 2]);
                P[4 * j + 3] = fmaf(h4.w, hv0, P[4 * j + 3]);
            }
            #pragma unroll
            for (int rr = 0; rr < NREL; rr++)
                S[rr] += (r == rr) ? hv0 : 0.0f;
            e0 = e1; hv0 = hv1;
        }
    }

    // write reduction rows (pre-scaled)
    const float idg = invdeg[n];
    #pragma unroll
    for (int k = 0; k < 32; k++) Prows[hw][k][lane] = P[k] * idg;
    float stot = 0.0f;
    #pragma unroll
    for (int r = 0; r < NREL; r++) stot += S[r];
    Prows[hw][32][lane] = stot * idg;
    #pragma unroll
    for (int r = 0; r < NREL; r++)
        Prows[hw][33 + r][lane] = S[r] * invcnt[n * NREL + r];
    Prows[hw][41][lane] = h[n * EMB + lane];   // h_dst row
    __syncthreads();

    // ---------- contraction (lane = output column o) ----------
    float accN[NPB], accR[NPB];
    #pragma unroll
    for (int i = 0; i < NPB; i++) { accN[i] = 0.0f; accR[i] = 0.0f; }

    #pragma unroll 1
    for (int j = 0; j < 6; j++) {
        const int row = hw + 8 * j;
        if (row > 40) break;                     // only hw=0 reaches j=5 (row 40)
        const float* Wsrc = (row < 32) ? (W2 + (size_t)row * 1024)
                          : (row == 32) ? b2
                          : (rgcnW_l + (size_t)(row - 33) * 1024);
        float Wreg[32];
        #pragma unroll
        for (int i = 0; i < 32; i++) Wreg[i] = Wsrc[i * EMB + lane];
        const bool isN = (row <= 32);
        #pragma unroll
        for (int nd = 0; nd < NPB; nd++) {
            const float4* Pr = (const float4*)&Prows[nd][row][0];
            float acc = 0.0f;
            #pragma unroll
            for (int jj = 0; jj < 8; jj++) {
                float4 p4 = Pr[jj];                       // broadcast b128
                acc = fmaf(p4.x, Wreg[4 * jj + 0], acc);
                acc = fmaf(p4.y, Wreg[4 * jj + 1], acc);
                acc = fmaf(p4.z, Wreg[4 * jj + 2], acc);
                acc = fmaf(p4.w, Wreg[4 * jj + 3], acc);
            }
            if (isN) accN[nd] += acc; else accR[nd] += acc;
        }
    }

    // ---------- root terms (read h_dst row BEFORE Red aliasing) ----------
    float rootN = 0.0f, rootR = 0.0f;
    {
        const float4* hd4 = (const float4*)&Prows[hw][41][0];
        #pragma unroll
        for (int jj = 0; jj < 8; jj++) {
            float4 v = hd4[jj];
            rootN = fmaf(v.x, nnRoot_l[(4 * jj + 0) * EMB + lane], rootN);
            rootN = fmaf(v.y, nnRoot_l[(4 * jj + 1) * EMB + lane], rootN);
            rootN = fmaf(v.z, nnRoot_l[(4 * jj + 2) * EMB + lane], rootN);
            rootN = fmaf(v.w, nnRoot_l[(4 * jj + 3) * EMB + lane], rootN);
            rootR = fmaf(v.x, rgcnRoot_l[(4 * jj + 0) * EMB + lane], rootR);
            rootR = fmaf(v.y, rgcnRoot_l[(4 * jj + 1) * EMB + lane], rootR);
            rootR = fmaf(v.z, rgcnRoot_l[(4 * jj + 2) * EMB + lane], rootR);
            rootR = fmaf(v.w, rgcnRoot_l[(4 * jj + 3) * EMB + lane], rootR);
        }
    }
    const float hd_o = Prows[hw][41][lane];
    __syncthreads();

    // ---------- cross-half-wave reduction (alias Red over Prows) ----------
    float* Red = &Prows[0][0][0];                 // 4096 floats used
    #pragma unroll
    for (int nd = 0; nd < NPB; nd++) {
        Red[(hw * NPB + nd) * EMB + lane] = accN[nd];
        Red[2048 + (hw * NPB + nd) * EMB + lane] = accR[nd];
    }
    __syncthreads();

    float sn = 0.0f, sr = 0.0f;
    #pragma unroll
    for (int w = 0; w < NPB; w++) {
        sn += Red[(w * NPB + hw) * EMB + lane];
        sr += Red[2048 + (w * NPB + hw) * EMB + lane];
    }
    float o_r = fmaxf(sr + rootR + rgcnBias_l[lane], 0.0f);
    float o_n = fmaxf(sn + rootN + nnBias_l[lane], 0.0f);
    hout[n * EMB + lane] = hd_o + o_r + o_n;
}

// ---------------- launch ----------------

extern "C" void kernel_launch(void* const* d_in, const int* in_sizes, int n_in,
                              void* d_out, int out_size, void* d_ws, size_t ws_size,
                              hipStream_t stream) {
    const float* x        = (const float*)d_in[0];
    const int*   ei       = (const int*)d_in[1];
    const int*   et       = (const int*)d_in[2];
    const float* ed       = (const float*)d_in[3];
    const float* fcW      = (const float*)d_in[4];
    const float* fcb      = (const float*)d_in[5];
    const float* rgcnW    = (const float*)d_in[6];
    const float* rgcnRoot = (const float*)d_in[7];
    const float* rgcnBias = (const float*)d_in[8];
    const float* W1       = (const float*)d_in[9];
    const float* b1       = (const float*)d_in[10];
    const float* W2       = (const float*)d_in[11];
    const float* b2       = (const float*)d_in[12];
    const float* nnRoot   = (const float*)d_in[13];
    const float* nnBias   = (const float*)d_in[14];

    float* ws = (float*)d_ws;
    float* h_a    = ws;  ws += (size_t)N_NODES * EMB;
    float* h_b    = ws;  ws += (size_t)N_NODES * EMB;
    float* invdeg = ws;  ws += (size_t)N_NODES;
    float* invcnt = ws;  ws += (size_t)N_NODES * NREL;
    int2* edge2   = (int2*)ws;     ws += (size_t)N_EDGES * 2;
    int* row_ptr  = (int*)ws;      ws += (size_t)(N_NODES + 1);
    int* deg      = (int*)ws;      ws += (size_t)N_NODES;       // deg..cursor contiguous
    int* relcnt   = (int*)ws;      ws += (size_t)N_NODES * NREL;
    int* cursor   = (int*)ws;      ws += (size_t)N_NODES;
    (void)in_sizes; (void)n_in; (void)out_size; (void)ws_size;

    zero_kernel<<<(10 * N_NODES + 255) / 256, 256, 0, stream>>>(deg, 10 * N_NODES);
    hist_kernel<<<(N_EDGES + 255) / 256, 256, 0, stream>>>(ei, et, deg, relcnt);
    scan_kernel<<<1, 1024, 0, stream>>>(deg, row_ptr);
    inv_kernel<<<(N_NODES + 255) / 256, 256, 0, stream>>>(deg, relcnt, invdeg, invcnt);
    scatter_kernel<<<(N_EDGES + 255) / 256, 256, 0, stream>>>(ei, et, ed, row_ptr,
                                                              cursor, edge2);
    fc_kernel<<<N_NODES / 8, 256, 0, stream>>>(x, fcW, fcb, h_a);

    const float* hin = h_a;
    float* houtb = h_b;
    for (int l = 0; l < NLAYER; l++) {
        float* dst = (l == NLAYER - 1) ? (float*)d_out : houtb;
        layer_kernel<<<N_NODES / NPB, 256, 0, stream>>>(
            hin, edge2, row_ptr, invdeg, invcnt, W1, b1, W2, b2,
            rgcnW + (size_t)l * NREL * EMB * EMB,
            rgcnRoot + (size_t)l * EMB * EMB,
            rgcnBias + (size_t)l * EMB,
            nnRoot + (size_t)l * EMB * EMB,
            nnBias + (size_t)l * EMB,
            dst);
        float* old_in = (float*)hin;
        hin = dst;
        houtb = old_in;
    }
}